// Round 4
// baseline (711.820 us; speedup 1.0000x reference)
//
#include <hip/hip_runtime.h>

#define D4 512        // 2048 floats = 512 float4 per row
#define K_EDGES 32    // sorted edges per wave-chunk

// ---------- sort machinery (counting sort by src, per relation) ----------

__global__ void zero_ints(int* __restrict__ p, int n) {
    int i = blockIdx.x * blockDim.x + threadIdx.x;
    if (i < n) p[i] = 0;
}

// cnt layout: [0,nd) rel0(ddi) | [nd,2nd) rel1(dpi) | [2nd,2nd+np) rel2(ppi)
__global__ void hist3(const int* __restrict__ s0, const int* __restrict__ s1,
                      const int* __restrict__ s2, int E,
                      int* __restrict__ cnt, int nd) {
    int i = blockIdx.x * blockDim.x + threadIdx.x;
    const int total = 3 * E;
    for (; i < total; i += gridDim.x * blockDim.x) {
        if (i < E)           atomicAdd(&cnt[s0[i]], 1);
        else if (i < 2 * E)  atomicAdd(&cnt[nd + s1[i - E]], 1);
        else                 atomicAdd(&cnt[2 * nd + s2[i - 2 * E]], 1);
    }
}

// block b scans relation b's bucket counts -> exclusive bases (within-relation)
__global__ void scan3(const int* __restrict__ cnt, int* __restrict__ base,
                      int nd, int np) {
    __shared__ int part[1024];
    const int b = blockIdx.x;
    const int off = (b == 0) ? 0 : (b == 1) ? nd : 2 * nd;
    const int N = (b == 2) ? np : nd;
    const int t = threadIdx.x;
    const int C = (N + blockDim.x - 1) / blockDim.x;
    const int lo = t * C, hi = min(lo + C, N);
    int s = 0;
    for (int i = lo; i < hi; ++i) s += cnt[off + i];
    part[t] = s;
    __syncthreads();
    if (t == 0) {
        int run = 0;
        for (int i = 0; i < (int)blockDim.x; ++i) { int tmp = part[i]; part[i] = run; run += tmp; }
    }
    __syncthreads();
    int run = part[t];
    for (int i = lo; i < hi; ++i) { base[off + i] = run; run += cnt[off + i]; }
}

// scatter edge ids into src-grouped order (destroys base as the cursor)
__global__ void scatter3(const int* __restrict__ s0, const int* __restrict__ s1,
                         const int* __restrict__ s2, int E,
                         int* __restrict__ base, int nd, int* __restrict__ sorted) {
    int i = blockIdx.x * blockDim.x + threadIdx.x;
    const int total = 3 * E;
    for (; i < total; i += gridDim.x * blockDim.x) {
        if (i < E)          { int p = atomicAdd(&base[s0[i]], 1);           sorted[p] = i; }
        else if (i < 2 * E) { int k = i - E;     int p = atomicAdd(&base[nd + s1[k]], 1);     sorted[E + p] = k; }
        else                { int k = i - 2 * E; int p = atomicAdd(&base[2 * nd + s2[k]], 1); sorted[2 * E + p] = k; }
    }
}

// ---------- scoring over src-sorted edges ----------
// One wave per chunk of K_EDGES sorted edges. head*rel cached in 32 VGPRs
// across same-src runs (rel itself read from LDS only on src change).
// Tail rows double-buffered (tA/tB): the next edge's 8 16B loads are issued
// before the current edge's reduce chain -> ~16 loads in flight per wave.
__global__ __launch_bounds__(256) void score_sorted(
    const float4* __restrict__ xdrug, const float4* __restrict__ xprot,
    const float4* __restrict__ rddi,  const float4* __restrict__ rdpi,
    const int* __restrict__ ddi_src, const int* __restrict__ ddi_dst,
    const int* __restrict__ dpi_src, const int* __restrict__ dpi_dst,
    const int* __restrict__ ppi_src, const int* __restrict__ ppi_dst,
    const int* __restrict__ sorted, float* __restrict__ out, int E)
{
    __shared__ float4 srel[2][D4];
    for (int i = threadIdx.x; i < D4; i += blockDim.x) {
        srel[0][i] = rddi[i];
        srel[1][i] = rdpi[i];
    }
    __syncthreads();

    const int lane = threadIdx.x & 63;
    const int wpb = blockDim.x >> 6;
    int wid = blockIdx.x * wpb + (threadIdx.x >> 6);
    const int nw = gridDim.x * wpb;
    const int cpr = (E + K_EDGES - 1) / K_EDGES;
    const int total_chunks = 3 * cpr;

    for (int c = wid; c < total_chunks; c += nw) {
        const int r = c / cpr;
        const int ci = c - r * cpr;
        const int e_lo = ci * K_EDGES;
        const int e_hi = min(e_lo + K_EDGES, E);

        const float4 *xs, *xd;
        const float4* srelp;
        const int *srcA, *dstA, *sl;
        float* o;
        if (r == 0)      { xs = xdrug; xd = xdrug; srelp = srel[0]; srcA = ddi_src; dstA = ddi_dst; sl = sorted;         o = out; }
        else if (r == 1) { xs = xdrug; xd = xprot; srelp = srel[1]; srcA = dpi_src; dstA = dpi_dst; sl = sorted + E;     o = out + E; }
        else             { xs = xprot; xd = xprot; srelp = srel[1]; srcA = ppi_src; dstA = ppi_dst; sl = sorted + 2 * E; o = out + 2 * E; }

        int cur_src = -1;
        float4 hr[8];
        float4 tA[8], tB[8];

        auto load_hr = [&](int s) {
            const float4* __restrict__ hp = xs + (size_t)s * D4;
#pragma unroll
            for (int j = 0; j < 8; ++j) {
                float4 h = hp[j * 64 + lane];
                float4 rv = srelp[j * 64 + lane];
                hr[j].x = h.x * rv.x;
                hr[j].y = h.y * rv.y;
                hr[j].z = h.z * rv.z;
                hr[j].w = h.w * rv.w;
            }
        };
        auto score_one = [&](const float4 (&t)[8], int e) {
            float acc = 0.f;
#pragma unroll
            for (int j = 0; j < 8; ++j) {
                acc = fmaf(hr[j].x, t[j].x, acc);
                acc = fmaf(hr[j].y, t[j].y, acc);
                acc = fmaf(hr[j].z, t[j].z, acc);
                acc = fmaf(hr[j].w, t[j].w, acc);
            }
#pragma unroll
            for (int off = 32; off; off >>= 1) acc += __shfl_down(acc, off, 64);
            if (lane == 0) o[e] = fminf(fmaxf(acc, 0.f), 1.f);
        };

        int i = e_lo;
        int eA = sl[i];
        {
            const float4* __restrict__ tp = xd + (size_t)dstA[eA] * D4;
#pragma unroll
            for (int j = 0; j < 8; ++j) tA[j] = tp[j * 64 + lane];
        }

        while (i < e_hi) {
            // prefetch edge i+1 tail into tB (independent of eA's compute)
            int eB = -1;
            if (i + 1 < e_hi) {
                eB = sl[i + 1];
                const float4* __restrict__ tp = xd + (size_t)dstA[eB] * D4;
#pragma unroll
                for (int j = 0; j < 8; ++j) tB[j] = tp[j * 64 + lane];
            }
            int s = srcA[eA];
            if (s != cur_src) { cur_src = s; load_hr(s); }   // wave-uniform
            score_one(tA, eA);
            ++i;
            if (i >= e_hi) break;

            // prefetch edge i+1 tail into tA (tA is free now)
            int eC = -1;
            if (i + 1 < e_hi) {
                eC = sl[i + 1];
                const float4* __restrict__ tp = xd + (size_t)dstA[eC] * D4;
#pragma unroll
                for (int j = 0; j < 8; ++j) tA[j] = tp[j * 64 + lane];
            }
            s = srcA[eB];
            if (s != cur_src) { cur_src = s; load_hr(s); }
            score_one(tB, eB);
            ++i;
            eA = eC;
        }
    }
}

// ---------- fallback (direct kernel) if ws too small ----------
__global__ __launch_bounds__(256) void edge_score_all(
    const float4* __restrict__ xdrug, const float4* __restrict__ xprot,
    const float4* __restrict__ rddi,  const float4* __restrict__ rdpi,
    const int* __restrict__ ddi_src, const int* __restrict__ ddi_dst,
    const int* __restrict__ dpi_src, const int* __restrict__ dpi_dst,
    const int* __restrict__ ppi_src, const int* __restrict__ ppi_dst,
    float* __restrict__ out, int E)
{
    __shared__ float4 srel[2][D4];
    for (int i = threadIdx.x; i < D4; i += blockDim.x) {
        srel[0][i] = rddi[i];
        srel[1][i] = rdpi[i];
    }
    __syncthreads();
    const int lane = threadIdx.x & 63;
    const int wpb = blockDim.x >> 6;
    int wid = blockIdx.x * wpb + (threadIdx.x >> 6);
    const int nw = gridDim.x * wpb;
    const int total = 3 * E;
    for (int e = wid; e < total; e += nw) {
        const float4 *hp, *tp;
        int sel;
        if (e < E)          { hp = xdrug + (size_t)ddi_src[e] * D4; tp = xdrug + (size_t)ddi_dst[e] * D4; sel = 0; }
        else if (e < 2 * E) { int k = e - E;     hp = xdrug + (size_t)dpi_src[k] * D4; tp = xprot + (size_t)dpi_dst[k] * D4; sel = 1; }
        else                { int k = e - 2 * E; hp = xprot + (size_t)ppi_src[k] * D4; tp = xprot + (size_t)ppi_dst[k] * D4; sel = 1; }
        float acc = 0.f;
#pragma unroll
        for (int j = 0; j < 8; ++j) {
            const int idx = j * 64 + lane;
            float4 h = hp[idx], t = tp[idx], rv = srel[sel][idx];
            acc = fmaf(h.x * rv.x, t.x, acc);
            acc = fmaf(h.y * rv.y, t.y, acc);
            acc = fmaf(h.z * rv.z, t.z, acc);
            acc = fmaf(h.w * rv.w, t.w, acc);
        }
#pragma unroll
        for (int off = 32; off; off >>= 1) acc += __shfl_down(acc, off, 64);
        if (lane == 0) out[e] = fminf(fmaxf(acc, 0.f), 1.f);
    }
}

extern "C" void kernel_launch(void* const* d_in, const int* in_sizes, int n_in,
                              void* d_out, int out_size, void* d_ws, size_t ws_size,
                              hipStream_t stream) {
    const float* x_drug    = (const float*)d_in[0];
    const float* x_protein = (const float*)d_in[1];
    const float* rel_ddi   = (const float*)d_in[2];
    const float* rel_dpi   = (const float*)d_in[3];
    const int* ddi_src = (const int*)d_in[4];
    const int* ddi_dst = (const int*)d_in[5];
    const int* dpi_src = (const int*)d_in[6];
    const int* dpi_dst = (const int*)d_in[7];
    const int* ppi_src = (const int*)d_in[8];
    const int* ppi_dst = (const int*)d_in[9];

    const int D  = in_sizes[2];              // 2048
    const int nd = in_sizes[0] / D;          // N_DRUG
    const int np = in_sizes[1] / D;          // N_PROT
    const int E  = in_sizes[4];              // edges per relation
    float* out = (float*)d_out;

    const int CB = 2 * nd + np;              // bucket count (all relations)
    const size_t need = (size_t)(2 * CB + 3 * E) * sizeof(int);

    if (ws_size < need) {                    // fallback: direct kernel
        edge_score_all<<<2048, 256, 0, stream>>>(
            (const float4*)x_drug, (const float4*)x_protein,
            (const float4*)rel_ddi, (const float4*)rel_dpi,
            ddi_src, ddi_dst, dpi_src, dpi_dst, ppi_src, ppi_dst, out, E);
        return;
    }

    int* cnt    = (int*)d_ws;                // CB ints
    int* base   = cnt + CB;                  // CB ints (becomes cursor)
    int* sorted = base + CB;                 // 3E ints

    zero_ints<<<(CB + 255) / 256, 256, 0, stream>>>(cnt, CB);
    hist3<<<1024, 256, 0, stream>>>(ddi_src, dpi_src, ppi_src, E, cnt, nd);
    scan3<<<3, 1024, 0, stream>>>(cnt, base, nd, np);
    scatter3<<<1024, 256, 0, stream>>>(ddi_src, dpi_src, ppi_src, E, base, nd, sorted);

    const int cpr = (E + K_EDGES - 1) / K_EDGES;
    const int total_chunks = 3 * cpr;
    const int waves_per_block = 4;           // 256 threads
    const int blocks = (total_chunks + waves_per_block - 1) / waves_per_block;

    score_sorted<<<blocks, 256, 0, stream>>>(
        (const float4*)x_drug, (const float4*)x_protein,
        (const float4*)rel_ddi, (const float4*)rel_dpi,
        ddi_src, ddi_dst, dpi_src, dpi_dst, ppi_src, ppi_dst,
        sorted, out, E);
}